// Round 1
// baseline (85.821 us; speedup 1.0000x reference)
//
#include <hip/hip_runtime.h>
#include <hip/hip_bf16.h>

// out[b,i,j,o] = Y[b*128+i][o] + Y[b*128+j][o] + bias[o]
// where Y[m][o] = sum_h L[m][h] * W[o][h]   (M=1024, H=512)

#define BM 64
#define BO 64
#define BK 32
#define LDS_PAD 36   // row stride in floats: 36*4=144B, multiple of 16B -> aligned float4

__global__ __launch_bounds__(256) void gemm_lwt(const float* __restrict__ A,
                                                const float* __restrict__ W,
                                                float* __restrict__ Y) {
    __shared__ __align__(16) float As[BM][LDS_PAD];
    __shared__ __align__(16) float Ws[BO][LDS_PAD];

    const int tid = threadIdx.x;
    const int m0 = blockIdx.x * BM;   // gridDim.x = 1024/64 = 16
    const int o0 = blockIdx.y * BO;   // gridDim.y = 512/64  = 8
    const int tm = tid >> 4;          // 0..15 -> rows tm*4+ii
    const int to = tid & 15;          // 0..15 -> cols to+16*jj (strided: conflict-free LDS reads)

    float acc[4][4] = {};

    for (int kt = 0; kt < 512; kt += BK) {
        // Stage A tile (64x32) and W tile (64x32): 512 float4 each, 2 per thread.
        #pragma unroll
        for (int l = 0; l < 2; ++l) {
            const int fid = tid + l * 256;
            const int row = fid >> 3;       // 0..63
            const int k4  = fid & 7;        // 0..7  -> k offset k4*4
            const float4 va = *(const float4*)&A[(m0 + row) * 512 + kt + k4 * 4];
            *(float4*)&As[row][k4 * 4] = va;
            const float4 vw = *(const float4*)&W[(o0 + row) * 512 + kt + k4 * 4];
            *(float4*)&Ws[row][k4 * 4] = vw;
        }
        __syncthreads();

        #pragma unroll
        for (int k0 = 0; k0 < BK; k0 += 4) {
            float4 a4[4], w4[4];
            #pragma unroll
            for (int ii = 0; ii < 4; ++ii) a4[ii] = *(const float4*)&As[tm * 4 + ii][k0];
            #pragma unroll
            for (int jj = 0; jj < 4; ++jj) w4[jj] = *(const float4*)&Ws[to + 16 * jj][k0];
            #pragma unroll
            for (int ii = 0; ii < 4; ++ii)
                #pragma unroll
                for (int jj = 0; jj < 4; ++jj)
                    acc[ii][jj] += a4[ii].x * w4[jj].x + a4[ii].y * w4[jj].y +
                                   a4[ii].z * w4[jj].z + a4[ii].w * w4[jj].w;
        }
        __syncthreads();
    }

    #pragma unroll
    for (int ii = 0; ii < 4; ++ii)
        #pragma unroll
        for (int jj = 0; jj < 4; ++jj)
            Y[(m0 + tm * 4 + ii) * 512 + o0 + to + 16 * jj] = acc[ii][jj];
}

// out4[f] where f indexes float4: f = ((b*128+i)*128+j)*128 + o4
__global__ __launch_bounds__(256) void pair_add(const float4* __restrict__ Y4,
                                                const float4* __restrict__ b4,
                                                float4* __restrict__ out4) {
    const int total = 8 * 128 * 128 * 128;   // 16,777,216 float4
    const int stride = gridDim.x * blockDim.x;
    for (int f = blockIdx.x * blockDim.x + threadIdx.x; f < total; f += stride) {
        const int o4 = f & 127;          // 512 floats = 128 float4 per (b,i,j)
        const int p  = f >> 7;           // b*16384 + i*128 + j
        const int j  = p & 127;
        const int q  = p >> 7;           // b*128 + i  == Y row for (b,i)
        const int yj = ((q >> 7) << 7) | j;  // b*128 + j
        const float4 a  = Y4[q * 128 + o4];
        const float4 c  = Y4[yj * 128 + o4];
        const float4 bb = b4[o4];
        float4 r;
        r.x = a.x + c.x + bb.x;
        r.y = a.y + c.y + bb.y;
        r.z = a.z + c.z + bb.z;
        r.w = a.w + c.w + bb.w;
        out4[f] = r;
    }
}

extern "C" void kernel_launch(void* const* d_in, const int* in_sizes, int n_in,
                              void* d_out, int out_size, void* d_ws, size_t ws_size,
                              hipStream_t stream) {
    const float* L = (const float*)d_in[0];   // [8,128,512]
    const float* W = (const float*)d_in[1];   // [512,512]
    const float* b = (const float*)d_in[2];   // [512]
    float* out = (float*)d_out;               // [8,128,128,512]
    float* Y   = (float*)d_ws;                // [1024,512] scratch, 2 MiB

    dim3 g1(16, 8);
    gemm_lwt<<<g1, 256, 0, stream>>>(L, W, Y);

    pair_add<<<2048, 256, 0, stream>>>((const float4*)Y, (const float4*)b, (float4*)out);
    (void)in_sizes; (void)n_in; (void)out_size; (void)ws_size;
}

// Round 3
// 77.675 us; speedup vs baseline: 1.1049x; 1.1049x over previous
//
#include <hip/hip_runtime.h>
#include <hip/hip_bf16.h>

// out[b,i,j,o] = Y[b*128+i][o] + Y[b*128+j][o] + bias[o]
// where Y[m][o] = sum_h L[m][h] * W[o][h]   (M=1024, O=512, H=512)

typedef float f4 __attribute__((ext_vector_type(4)));   // native vec: ok for nontemporal builtins

#define BM 32
#define BO 64
#define BK 32
#define LDS_PAD 36   // row stride in floats: 144B, multiple of 16B -> aligned float4

__global__ __launch_bounds__(256) void gemm_lwt(const float* __restrict__ A,
                                                const float* __restrict__ W,
                                                float* __restrict__ Y) {
    __shared__ __align__(16) float As[BM][LDS_PAD];
    __shared__ __align__(16) float Ws[BO][LDS_PAD];

    const int tid = threadIdx.x;
    const int m0 = blockIdx.x * BM;   // gridDim.x = 1024/32 = 32
    const int o0 = blockIdx.y * BO;   // gridDim.y = 512/64  = 8
    const int tm = tid >> 4;          // 0..15 -> rows tm*2+ii
    const int to = tid & 15;          // 0..15 -> cols to+16*jj

    float acc[2][4] = {};

    for (int kt = 0; kt < 512; kt += BK) {
        // A tile 32x32 = 256 f4 (1/thread); W tile 64x32 = 512 f4 (2/thread)
        {
            const int row = tid >> 3;        // 0..31
            const int k4  = tid & 7;
            *(f4*)&As[row][k4 * 4] = *(const f4*)&A[(m0 + row) * 512 + kt + k4 * 4];
        }
        #pragma unroll
        for (int l = 0; l < 2; ++l) {
            const int fid = tid + l * 256;
            const int row = fid >> 3;        // 0..63
            const int k4  = fid & 7;
            *(f4*)&Ws[row][k4 * 4] = *(const f4*)&W[(o0 + row) * 512 + kt + k4 * 4];
        }
        __syncthreads();

        #pragma unroll
        for (int k0 = 0; k0 < BK; k0 += 4) {
            f4 a4[2], w4[4];
            #pragma unroll
            for (int ii = 0; ii < 2; ++ii) a4[ii] = *(const f4*)&As[tm * 2 + ii][k0];
            #pragma unroll
            for (int jj = 0; jj < 4; ++jj) w4[jj] = *(const f4*)&Ws[to + 16 * jj][k0];
            #pragma unroll
            for (int ii = 0; ii < 2; ++ii)
                #pragma unroll
                for (int jj = 0; jj < 4; ++jj)
                    acc[ii][jj] += a4[ii].x * w4[jj].x + a4[ii].y * w4[jj].y +
                                   a4[ii].z * w4[jj].z + a4[ii].w * w4[jj].w;
        }
        __syncthreads();
    }

    #pragma unroll
    for (int ii = 0; ii < 2; ++ii)
        #pragma unroll
        for (int jj = 0; jj < 4; ++jj)
            Y[(m0 + tm * 2 + ii) * 512 + o0 + to + 16 * jj] = acc[ii][jj];
}

// One block per (b,i): writes out[b,i, 0..127, 0..511] = 256 KB contiguous.
// yib = Y[b,i,o4] + bias[o4] hoisted to a register; inner loop: read Y[b,j,o4]
// (L2-resident, 2 MiB total), add, nontemporal store.
__global__ __launch_bounds__(256) void pair_add(const f4* __restrict__ Y4,
                                                const f4* __restrict__ b4,
                                                f4* __restrict__ out4) {
    const int blk = blockIdx.x;          // b*128 + i, 0..1023
    const int t   = threadIdx.x;
    const int o4  = t & 127;             // 0..127 (128 f4 per row)
    const int jh  = t >> 7;              // 0 or 1

    const f4 yib = Y4[blk * 128 + o4] + b4[o4];

    const f4* __restrict__ Yb = Y4 + (blk >> 7) * (128 * 128);  // rows of this b
    f4* __restrict__ orow = out4 + blk * (128 * 128);

    #pragma unroll 4
    for (int j = jh; j < 128; j += 2) {
        const f4 r = yib + Yb[j * 128 + o4];
        __builtin_nontemporal_store(r, &orow[j * 128 + o4]);
    }
}

extern "C" void kernel_launch(void* const* d_in, const int* in_sizes, int n_in,
                              void* d_out, int out_size, void* d_ws, size_t ws_size,
                              hipStream_t stream) {
    const float* L = (const float*)d_in[0];   // [8,128,512]
    const float* W = (const float*)d_in[1];   // [512,512]
    const float* b = (const float*)d_in[2];   // [512]
    float* out = (float*)d_out;               // [8,128,128,512]
    float* Y   = (float*)d_ws;                // [1024,512] scratch, 2 MiB

    dim3 g1(32, 8);
    gemm_lwt<<<g1, 256, 0, stream>>>(L, W, Y);

    pair_add<<<1024, 256, 0, stream>>>((const f4*)Y, (const f4*)b, (f4*)out);
    (void)in_sizes; (void)n_in; (void)out_size; (void)ws_size;
}